// Round 10
// baseline (150.606 us; speedup 1.0000x reference)
//
#include <hip/hip_runtime.h>

typedef _Float16 half8 __attribute__((ext_vector_type(8)));
typedef float f32x4 __attribute__((ext_vector_type(4)));
typedef float float4_t __attribute__((ext_vector_type(4)));
typedef unsigned int uint32x2 __attribute__((ext_vector_type(2)));

#define DIM 512
#define S 64            // spatial side
#define NROW 4096       // S*S
#define LDSW 88         // fp16 elems per LDS row (176B stride)

// LDS-only barrier: wait own LDS ops, sync, compiler memory fence both sides.
// Does NOT drain vmcnt -> global stores/loads stay in flight across it.
__device__ __forceinline__ void bar_lds() {
    asm volatile("s_waitcnt lgkmcnt(0)" ::: "memory");
    __builtin_amdgcn_s_barrier();
    asm volatile("" ::: "memory");
}

// ---------------- kernel 1: column sums of Wq and Wk (512x512 each) + bias sums ------------
// grid 256: blocks 0..127 -> Wq/bq -> wsumq, 128..255 -> Wk/bk -> wsumk (4 rows each)
__global__ void colsum2_kernel(const float* __restrict__ Wq, const float* __restrict__ bq,
                               const float* __restrict__ Wk, const float* __restrict__ bk,
                               float* __restrict__ wsumq, float* __restrict__ wsumk) {
    int sel = blockIdx.x >> 7;
    int b = blockIdx.x & 127;
    const float* W = sel ? Wk : Wq;
    const float* bias = sel ? bk : bq;
    float* wsum = sel ? wsumk : wsumq;
    int t = threadIdx.x;
    int c0 = t, c1 = t + 256;
    float s0 = 0.f, s1 = 0.f;
    const float* Wr = W + (size_t)b * 4 * DIM;
#pragma unroll
    for (int o = 0; o < 4; ++o) {
        s0 += Wr[o * DIM + c0];
        s1 += Wr[o * DIM + c1];
    }
    atomicAdd(&wsum[c0], s0);
    atomicAdd(&wsum[c1], s1);
    if (b == 0) {
        float bs = bias[c0] + bias[c1];
#pragma unroll
        for (int off = 32; off >= 1; off >>= 1) bs += __shfl_xor(bs, off);
        if ((t & 63) == 0) atomicAdd(&wsum[512], bs);
    }
}

// ---------------- kernel 2 (fused): rowdot (blocks 0..1023) + V-GEMM (blocks 1024..1535) ----
// rowdot: a = (x.wqsum + Bq)*SCALE, ks = x.wksum + Bk   (wave per row)
// vt:     V = X @ Wv^T + bv  -> swizzled fragment layout Vs
// Vs half-index for element (spatial row -> w=row>>6, k=row&63; channel d):
//   dt=d>>4, lr=d&15, s=k>>5, lg=(k>>3)&3, e=k&7
//   idx = ((((w*32+dt)*2+s)*4+lg)*16+lr)*8 + e
__global__ void rowdot_vt_kernel(const float* __restrict__ X,
                                 const float* __restrict__ wqsum,
                                 const float* __restrict__ wksum,
                                 float* __restrict__ a_arr,
                                 float* __restrict__ ks_arr,
                                 const float* __restrict__ Wv,
                                 const float* __restrict__ bv,
                                 _Float16* __restrict__ Vs) {
    int bid = blockIdx.x;
    if (bid < 1024) {
        int wave = threadIdx.x >> 6;
        int lane = threadIdx.x & 63;
        int row = bid * 4 + wave;
        const float4_t* xr = (const float4_t*)(X + (size_t)row * DIM) + lane * 2;
        const float4_t* wq = (const float4_t*)wqsum + lane * 2;
        const float4_t* wk = (const float4_t*)wksum + lane * 2;
        float4_t x0 = xr[0], x1 = xr[1];
        float4_t q0 = wq[0], q1 = wq[1];
        float4_t k0 = wk[0], k1 = wk[1];
        float sq = 0.f, sk = 0.f;
#pragma unroll
        for (int i = 0; i < 4; i++) {
            sq += x0[i] * q0[i] + x1[i] * q1[i];
            sk += x0[i] * k0[i] + x1[i] * k1[i];
        }
#pragma unroll
        for (int off = 32; off >= 1; off >>= 1) {
            sq += __shfl_xor(sq, off);
            sk += __shfl_xor(sk, off);
        }
        if (lane == 0) {
            a_arr[row]  = (sq + wqsum[DIM]) * 0.125f;
            ks_arr[row] = sk + wksum[DIM];
        }
        return;
    }
    int b2 = bid - 1024;
    int mb = b2 & 255;
    int cb = b2 >> 8;
    int wv_ = threadIdx.x >> 6;
    int lane = threadIdx.x & 63;
    int lr = lane & 15;
    int lg = lane >> 4;
    int row0 = mb * 16;
    int col0 = cb * 256 + wv_ * 64;

    f32x4 acc[4];
#pragma unroll
    for (int n = 0; n < 4; n++) acc[n] = (f32x4){0.f, 0.f, 0.f, 0.f};

    for (int kk = 0; kk < 16; ++kk) {
        int kbase = kk * 32 + lg * 8;
        const float4_t* pa = (const float4_t*)(X + (size_t)(row0 + lr) * DIM + kbase);
        float4_t x0 = pa[0], x1 = pa[1];
        half8 a;
#pragma unroll
        for (int i = 0; i < 4; i++) { a[i] = (_Float16)x0[i]; a[i + 4] = (_Float16)x1[i]; }
#pragma unroll
        for (int n = 0; n < 4; n++) {
            const float4_t* pb = (const float4_t*)(Wv + (size_t)(col0 + n * 16 + lr) * DIM + kbase);
            float4_t b0 = pb[0], b1 = pb[1];
            half8 hb;
#pragma unroll
            for (int i = 0; i < 4; i++) { hb[i] = (_Float16)b0[i]; hb[i + 4] = (_Float16)b1[i]; }
            acc[n] = __builtin_amdgcn_mfma_f32_16x16x32_f16(a, hb, acc[n], 0, 0, 0);
        }
    }
    int w   = mb >> 2;
    int s_  = (mb & 3) >> 1;
    int lg2 = ((mb & 3) * 2 + (lg >> 1)) & 3;
    int e0  = (lg & 1) * 4;
#pragma unroll
    for (int n = 0; n < 4; n++) {
        int d = col0 + n * 16 + lr;
        int dt = d >> 4;
        float bvc = bv[d];
        _Float16 tmp[4];
#pragma unroll
        for (int r = 0; r < 4; r++) tmp[r] = (_Float16)(acc[n][r] + bvc);
        int idx8 = (((w * 32 + dt) * 2 + s_) * 4 + lg2) * 16 + lr;
        __builtin_nontemporal_store(*(uint32x2*)tmp, (uint32x2*)(Vs + (size_t)idx8 * 8 + e0));
    }
}

// ---------------- kernel 3: main — h-batch=2 per block; V fragments loaded once -----------
// grid 2048 x 256. Block (w, h0..h0+1): all 16 V frags in regs; per h: softmax -> wfr ->
// 4-chunk MFMA -> LDS transpose -> contiguous PLAIN stores (A/B vs R9's nt stores:
// theory = plain stores aggregate in L2/L3 and drain as full lines like the 6.6 TB/s
// fill kernel; nt bypasses write-combining at 512B-run granularity).
__global__ __launch_bounds__(256) void attn_main_kernel(
        const float* __restrict__ a_arr,
        const float* __restrict__ ks_arr,
        const _Float16* __restrict__ Vs,
        float* __restrict__ out) {
    __shared__ __align__(16) char smem[32768];   // Osm 32 KB; Wsm overlaid (dead during chunks)
    _Float16* Wsm = (_Float16*)smem;
    char* Osm = smem;

    int b = blockIdx.x;
    int l = (b & 7) * 256 + (b >> 3);   // XCD b%8 -> contiguous l range -> 8 w-slices per XCD
    int w = l >> 5;
    int h0 = (l & 31) * 2;
    int t = threadIdx.x;
    int wv_ = t >> 6, lane = t & 63;
    int lr = lane & 15, lg = lane >> 4;

    const half8* Vg = (const half8*)Vs;

    // ---- preload ALL 16 V fragments for this w (reused across both h) ----
    // chunk j2 uses d-tiles dt = j2*8 + wv_*2 + c, slices s=0,1
    half8 vfr[4][2][2];
#pragma unroll
    for (int j2 = 0; j2 < 4; ++j2)
#pragma unroll
        for (int c = 0; c < 2; ++c) {
            int dt = j2 * 8 + wv_ * 2 + c;
            int g0 = ((w * 32 + dt) * 2) * 64 + lane;
            vfr[j2][c][0] = Vg[g0];
            vfr[j2][c][1] = Vg[g0 + 64];
        }

    float a0 = a_arr[h0 * 64 + w];
    float a1 = a_arr[(h0 + 1) * 64 + w];

    for (int hh = 0; hh < 2; ++hh) {
        float a = hh ? a1 : a0;
        int hw = (h0 + hh) * 64 + w;

        bar_lds();   // previous h's Osm readback reads complete before Wsm overlay write

        // ---- softmax: row p handled by 4 lanes (16 cols each) ----
        {
            int p = t >> 2, c = t & 3;
            const float4_t* kp = (const float4_t*)(ks_arr + p * 64 + c * 16);
            float4_t k0 = kp[0], k1 = kp[1], k2 = kp[2], k3 = kp[3];
            float L[16];
#pragma unroll
            for (int i = 0; i < 4; i++) {
                L[i] = a * k0[i]; L[4 + i] = a * k1[i];
                L[8 + i] = a * k2[i]; L[12 + i] = a * k3[i];
            }
            float m = L[0];
#pragma unroll
            for (int i = 1; i < 16; i++) m = fmaxf(m, L[i]);
            m = fmaxf(m, __shfl_xor(m, 1));
            m = fmaxf(m, __shfl_xor(m, 2));
            float e[16];
            float sum = 0.f;
#pragma unroll
            for (int i = 0; i < 16; i++) { e[i] = __expf(L[i] - m); sum += e[i]; }
            sum += __shfl_xor(sum, 1);
            sum += __shfl_xor(sum, 2);
            float r = 1.0f / sum;
            half8 hv0, hv1;
#pragma unroll
            for (int i = 0; i < 8; i++) {
                hv0[i] = (_Float16)(e[i] * r);
                hv1[i] = (_Float16)(e[8 + i] * r);
            }
            *(half8*)&Wsm[p * LDSW + c * 16]     = hv0;
            *(half8*)&Wsm[p * LDSW + c * 16 + 8] = hv1;
        }
        bar_lds();

        // ---- W fragments (B operand): lane holds col p = pt*16+lr, k = s*32+lg*8.. ----
        half8 wfr[4][2];
#pragma unroll
        for (int pt = 0; pt < 4; ++pt)
#pragma unroll
            for (int s_ = 0; s_ < 2; ++s_)
                wfr[pt][s_] = *(const half8*)&Wsm[(pt * 16 + lr) * LDSW + s_ * 32 + lg * 8];

        char* outb = (char*)(out + (size_t)hw * (64 * DIM));

        // ---- 4 chunks of 128 d-cols: MFMA (reg-only) -> LDS transpose -> plain stores ----
#pragma unroll
        for (int j2 = 0; j2 < 4; ++j2) {
            f32x4 acc[2][4];
#pragma unroll
            for (int c = 0; c < 2; ++c)
#pragma unroll
                for (int pt = 0; pt < 4; ++pt) acc[c][pt] = (f32x4){0.f, 0.f, 0.f, 0.f};
#pragma unroll
            for (int pt = 0; pt < 4; ++pt) {
                acc[0][pt] = __builtin_amdgcn_mfma_f32_16x16x32_f16(vfr[j2][0][0], wfr[pt][0], acc[0][pt], 0, 0, 0);
                acc[0][pt] = __builtin_amdgcn_mfma_f32_16x16x32_f16(vfr[j2][0][1], wfr[pt][1], acc[0][pt], 0, 0, 0);
                acc[1][pt] = __builtin_amdgcn_mfma_f32_16x16x32_f16(vfr[j2][1][0], wfr[pt][0], acc[1][pt], 0, 0, 0);
                acc[1][pt] = __builtin_amdgcn_mfma_f32_16x16x32_f16(vfr[j2][1][1], wfr[pt][1], acc[1][pt], 0, 0, 0);
            }
            bar_lds();   // previous chunk's Osm reads (chunk 0: wfr/softmax reads) complete
            // write O fragments into Osm, XOR-swizzled: acc[c][pt][r] = O[p][dloc]
            //   p = pt*16+lr, dloc = wv_*32 + c*16 + lg*4 + r
#pragma unroll
            for (int c = 0; c < 2; ++c)
#pragma unroll
                for (int pt = 0; pt < 4; ++pt) {
                    int p = pt * 16 + lr;
                    int addr = p * 512 + (wv_ * 32 + c * 16 + lg * 4) * 4;
                    addr ^= (p & 7) << 4;
                    *(f32x4*)(Osm + addr) = acc[c][pt];
                }
            bar_lds();
            // read back + PLAIN store: 512B runs, 1 KB per wave instruction (L2-aggregated)
#pragma unroll
            for (int i = 0; i < 8; ++i) {
                int f = i * 4096 + t * 16;
                int row = f >> 9;
                int rb = f ^ ((row & 7) << 4);
                f32x4 val = *(const f32x4*)(Osm + rb);
                *(f32x4*)(outb + (size_t)row * 2048 + j2 * 512 + (f & 511)) = val;
            }
        }
    }
}

// ---------------- launcher ----------------
extern "C" void kernel_launch(void* const* d_in, const int* in_sizes, int n_in,
                              void* d_out, int out_size, void* d_ws, size_t ws_size,
                              hipStream_t stream) {
    const float* x  = (const float*)d_in[0];
    const float* Wq = (const float*)d_in[2];
    const float* bq = (const float*)d_in[3];
    const float* Wk = (const float*)d_in[4];
    const float* bk = (const float*)d_in[5];
    const float* Wv = (const float*)d_in[6];
    const float* bv = (const float*)d_in[7];
    float* out = (float*)d_out;
    char* ws = (char*)d_ws;

    _Float16* Vs  = (_Float16*)ws;                 // 512*4096*2 = 4 MiB (swizzled)
    float* a_arr  = (float*)(ws + 4194304);        // 4096 f32
    float* ks_arr = (float*)(ws + 4210688);        // 4096 f32
    float* wqsum  = (float*)(ws + 4227072);        // 513 f32
    float* wksum  = (float*)(ws + 4229184);        // 513 f32

    hipMemsetAsync(ws + 4227072, 0, 4224, stream);
    colsum2_kernel<<<256, 256, 0, stream>>>(Wq, bq, Wk, bk, wqsum, wksum);
    rowdot_vt_kernel<<<1536, 256, 0, stream>>>(x, wqsum, wksum, a_arr, ks_arr, Wv, bv, Vs);
    attn_main_kernel<<<2048, 256, 0, stream>>>(a_arr, ks_arr, Vs, out);
}

// Round 11
// 139.742 us; speedup vs baseline: 1.0777x; 1.0777x over previous
//
#include <hip/hip_runtime.h>

typedef _Float16 half8 __attribute__((ext_vector_type(8)));
typedef float f32x4 __attribute__((ext_vector_type(4)));
typedef float float4_t __attribute__((ext_vector_type(4)));
typedef unsigned int uint32x2 __attribute__((ext_vector_type(2)));

#define DIM 512
#define S 64            // spatial side
#define NROW 4096       // S*S
#define LDSW 88         // fp16 elems per LDS row (176B stride)

// LDS-only barrier: wait own LDS ops, sync, compiler memory fence both sides.
// Does NOT drain vmcnt -> global stores/loads stay in flight across it.
__device__ __forceinline__ void bar_lds() {
    asm volatile("s_waitcnt lgkmcnt(0)" ::: "memory");
    __builtin_amdgcn_s_barrier();
    asm volatile("" ::: "memory");
}

// ---------------- kernel 1 (fused, independent halves): colsum partials + V-GEMM ----------
// blocks 0..7: column-sum partials of Wq/Wk. block b: matrix sel=b>>2, quarter qr=b&3 sums
//   rows [qr*128,+128) -> part[sel][qr][c] (no atomics, no memset). qr==0 also writes
//   pbias[sel] = sum(bias) via LDS reduce (single writer).
// blocks 8..519: V = X @ Wv^T + bv -> swizzled fragment layout Vs (unchanged math).
// Vs half-index for element (spatial row -> w=row>>6, k=row&63; channel d):
//   dt=d>>4, lr=d&15, s=k>>5, lg=(k>>3)&3, e=k&7
//   idx = ((((w*32+dt)*2+s)*4+lg)*16+lr)*8 + e
__global__ void colsum_vt_kernel(const float* __restrict__ Wq, const float* __restrict__ bq,
                                 const float* __restrict__ Wk, const float* __restrict__ bk,
                                 float* __restrict__ part,    // [2][4][512]
                                 float* __restrict__ pbias,   // [2]
                                 const float* __restrict__ X,
                                 const float* __restrict__ Wv,
                                 const float* __restrict__ bv,
                                 _Float16* __restrict__ Vs) {
    int bid = blockIdx.x;
    if (bid < 8) {
        int sel = bid >> 2, qr = bid & 3;
        const float* W = sel ? Wk : Wq;
        const float* bias = sel ? bk : bq;
        int t = threadIdx.x;
        int c0 = t, c1 = t + 256;
        float s0 = 0.f, s1 = 0.f;
        const float* Wr = W + (size_t)qr * 128 * DIM;
        for (int o = 0; o < 128; ++o) {
            s0 += Wr[o * DIM + c0];
            s1 += Wr[o * DIM + c1];
        }
        part[(sel * 4 + qr) * 512 + c0] = s0;
        part[(sel * 4 + qr) * 512 + c1] = s1;
        if (qr == 0) {
            float bs = bias[c0] + bias[c1];
#pragma unroll
            for (int off = 32; off >= 1; off >>= 1) bs += __shfl_xor(bs, off);
            __shared__ float red[4];
            if ((t & 63) == 0) red[t >> 6] = bs;
            __syncthreads();
            if (t == 0) pbias[sel] = red[0] + red[1] + red[2] + red[3];
        }
        return;
    }
    int b2 = bid - 8;
    int mb = b2 & 255;
    int cb = b2 >> 8;
    int wv_ = threadIdx.x >> 6;
    int lane = threadIdx.x & 63;
    int lr = lane & 15;
    int lg = lane >> 4;
    int row0 = mb * 16;
    int col0 = cb * 256 + wv_ * 64;

    f32x4 acc[4];
#pragma unroll
    for (int n = 0; n < 4; n++) acc[n] = (f32x4){0.f, 0.f, 0.f, 0.f};

    for (int kk = 0; kk < 16; ++kk) {
        int kbase = kk * 32 + lg * 8;
        const float4_t* pa = (const float4_t*)(X + (size_t)(row0 + lr) * DIM + kbase);
        float4_t x0 = pa[0], x1 = pa[1];
        half8 a;
#pragma unroll
        for (int i = 0; i < 4; i++) { a[i] = (_Float16)x0[i]; a[i + 4] = (_Float16)x1[i]; }
#pragma unroll
        for (int n = 0; n < 4; n++) {
            const float4_t* pb = (const float4_t*)(Wv + (size_t)(col0 + n * 16 + lr) * DIM + kbase);
            float4_t b0 = pb[0], b1 = pb[1];
            half8 hb;
#pragma unroll
            for (int i = 0; i < 4; i++) { hb[i] = (_Float16)b0[i]; hb[i + 4] = (_Float16)b1[i]; }
            acc[n] = __builtin_amdgcn_mfma_f32_16x16x32_f16(a, hb, acc[n], 0, 0, 0);
        }
    }
    int w   = mb >> 2;
    int s_  = (mb & 3) >> 1;
    int lg2 = ((mb & 3) * 2 + (lg >> 1)) & 3;
    int e0  = (lg & 1) * 4;
#pragma unroll
    for (int n = 0; n < 4; n++) {
        int d = col0 + n * 16 + lr;
        int dt = d >> 4;
        float bvc = bv[d];
        _Float16 tmp[4];
#pragma unroll
        for (int r = 0; r < 4; r++) tmp[r] = (_Float16)(acc[n][r] + bvc);
        int idx8 = (((w * 32 + dt) * 2 + s_) * 4 + lg2) * 16 + lr;
        __builtin_nontemporal_store(*(uint32x2*)tmp, (uint32x2*)(Vs + (size_t)idx8 * 8 + e0));
    }
}

// ---------------- kernel 2: per-row dots against the partial column sums ------------------
// a = (x . wq + sum(bq))*SCALE, ks = x . wk + sum(bk); wq/wk reduced from 4 partials inline.
__global__ void rowdot_kernel(const float* __restrict__ X,
                              const float* __restrict__ part,   // [2][4][512], L2-hot
                              const float* __restrict__ pbias,  // [2]
                              float* __restrict__ a_arr,
                              float* __restrict__ ks_arr) {
    int wave = threadIdx.x >> 6;
    int lane = threadIdx.x & 63;
    int row = blockIdx.x * 4 + wave;
    const float4_t* xr = (const float4_t*)(X + (size_t)row * DIM) + lane * 2;
    float4_t x0 = xr[0], x1 = xr[1];
    float sq = 0.f, sk = 0.f;
#pragma unroll
    for (int qr = 0; qr < 4; ++qr) {
        const float4_t* pq = (const float4_t*)(part + qr * 512) + lane * 2;
        const float4_t* pk = (const float4_t*)(part + 2048 + qr * 512) + lane * 2;
        float4_t q0 = pq[0], q1 = pq[1];
        float4_t k0 = pk[0], k1 = pk[1];
#pragma unroll
        for (int i = 0; i < 4; i++) {
            sq += x0[i] * q0[i] + x1[i] * q1[i];
            sk += x0[i] * k0[i] + x1[i] * k1[i];
        }
    }
#pragma unroll
    for (int off = 32; off >= 1; off >>= 1) {
        sq += __shfl_xor(sq, off);
        sk += __shfl_xor(sk, off);
    }
    if (lane == 0) {
        a_arr[row]  = (sq + pbias[0]) * 0.125f;
        ks_arr[row] = sk + pbias[1];
    }
}

// ---------------- kernel 3: main — unchanged from R9 (best: 145.9 us) ---------------------
// grid 2048 x 256. h-batch=2, V frags in regs, softmax -> wfr -> 4-chunk MFMA ->
// LDS transpose -> contiguous nt stores. XCD swizzle: 8 w-slices per XCD.
__global__ __launch_bounds__(256) void attn_main_kernel(
        const float* __restrict__ a_arr,
        const float* __restrict__ ks_arr,
        const _Float16* __restrict__ Vs,
        float* __restrict__ out) {
    __shared__ __align__(16) char smem[32768];   // Osm 32 KB; Wsm overlaid (dead during chunks)
    _Float16* Wsm = (_Float16*)smem;
    char* Osm = smem;

    int b = blockIdx.x;
    int l = (b & 7) * 256 + (b >> 3);   // XCD b%8 -> contiguous l range -> 8 w-slices per XCD
    int w = l >> 5;
    int h0 = (l & 31) * 2;
    int t = threadIdx.x;
    int wv_ = t >> 6, lane = t & 63;
    int lr = lane & 15, lg = lane >> 4;

    const half8* Vg = (const half8*)Vs;

    // ---- preload ALL 16 V fragments for this w (reused across both h) ----
    half8 vfr[4][2][2];
#pragma unroll
    for (int j2 = 0; j2 < 4; ++j2)
#pragma unroll
        for (int c = 0; c < 2; ++c) {
            int dt = j2 * 8 + wv_ * 2 + c;
            int g0 = ((w * 32 + dt) * 2) * 64 + lane;
            vfr[j2][c][0] = Vg[g0];
            vfr[j2][c][1] = Vg[g0 + 64];
        }

    float a0 = a_arr[h0 * 64 + w];
    float a1 = a_arr[(h0 + 1) * 64 + w];

    for (int hh = 0; hh < 2; ++hh) {
        float a = hh ? a1 : a0;
        int hw = (h0 + hh) * 64 + w;

        bar_lds();   // previous h's Osm readback reads complete before Wsm overlay write

        // ---- softmax: row p handled by 4 lanes (16 cols each) ----
        {
            int p = t >> 2, c = t & 3;
            const float4_t* kp = (const float4_t*)(ks_arr + p * 64 + c * 16);
            float4_t k0 = kp[0], k1 = kp[1], k2 = kp[2], k3 = kp[3];
            float L[16];
#pragma unroll
            for (int i = 0; i < 4; i++) {
                L[i] = a * k0[i]; L[4 + i] = a * k1[i];
                L[8 + i] = a * k2[i]; L[12 + i] = a * k3[i];
            }
            float m = L[0];
#pragma unroll
            for (int i = 1; i < 16; i++) m = fmaxf(m, L[i]);
            m = fmaxf(m, __shfl_xor(m, 1));
            m = fmaxf(m, __shfl_xor(m, 2));
            float e[16];
            float sum = 0.f;
#pragma unroll
            for (int i = 0; i < 16; i++) { e[i] = __expf(L[i] - m); sum += e[i]; }
            sum += __shfl_xor(sum, 1);
            sum += __shfl_xor(sum, 2);
            float r = 1.0f / sum;
            half8 hv0, hv1;
#pragma unroll
            for (int i = 0; i < 8; i++) {
                hv0[i] = (_Float16)(e[i] * r);
                hv1[i] = (_Float16)(e[8 + i] * r);
            }
            *(half8*)&Wsm[p * LDSW + c * 16]     = hv0;
            *(half8*)&Wsm[p * LDSW + c * 16 + 8] = hv1;
        }
        bar_lds();

        // ---- W fragments (B operand): lane holds col p = pt*16+lr, k = s*32+lg*8.. ----
        half8 wfr[4][2];
#pragma unroll
        for (int pt = 0; pt < 4; ++pt)
#pragma unroll
            for (int s_ = 0; s_ < 2; ++s_)
                wfr[pt][s_] = *(const half8*)&Wsm[(pt * 16 + lr) * LDSW + s_ * 32 + lg * 8];

        char* outb = (char*)(out + (size_t)hw * (64 * DIM));

        // ---- 4 chunks of 128 d-cols: MFMA (reg-only) -> LDS transpose -> nt stores ----
#pragma unroll
        for (int j2 = 0; j2 < 4; ++j2) {
            f32x4 acc[2][4];
#pragma unroll
            for (int c = 0; c < 2; ++c)
#pragma unroll
                for (int pt = 0; pt < 4; ++pt) acc[c][pt] = (f32x4){0.f, 0.f, 0.f, 0.f};
#pragma unroll
            for (int pt = 0; pt < 4; ++pt) {
                acc[0][pt] = __builtin_amdgcn_mfma_f32_16x16x32_f16(vfr[j2][0][0], wfr[pt][0], acc[0][pt], 0, 0, 0);
                acc[0][pt] = __builtin_amdgcn_mfma_f32_16x16x32_f16(vfr[j2][0][1], wfr[pt][1], acc[0][pt], 0, 0, 0);
                acc[1][pt] = __builtin_amdgcn_mfma_f32_16x16x32_f16(vfr[j2][1][0], wfr[pt][0], acc[1][pt], 0, 0, 0);
                acc[1][pt] = __builtin_amdgcn_mfma_f32_16x16x32_f16(vfr[j2][1][1], wfr[pt][1], acc[1][pt], 0, 0, 0);
            }
            bar_lds();   // previous chunk's Osm reads (chunk 0: wfr/softmax reads) complete
            // write O fragments into Osm, XOR-swizzled: acc[c][pt][r] = O[p][dloc]
            //   p = pt*16+lr, dloc = wv_*32 + c*16 + lg*4 + r
#pragma unroll
            for (int c = 0; c < 2; ++c)
#pragma unroll
                for (int pt = 0; pt < 4; ++pt) {
                    int p = pt * 16 + lr;
                    int addr = p * 512 + (wv_ * 32 + c * 16 + lg * 4) * 4;
                    addr ^= (p & 7) << 4;
                    *(f32x4*)(Osm + addr) = acc[c][pt];
                }
            bar_lds();
            // read back + nt store: 512B runs, 1 KB per wave instruction
#pragma unroll
            for (int i = 0; i < 8; ++i) {
                int f = i * 4096 + t * 16;
                int row = f >> 9;
                int rb = f ^ ((row & 7) << 4);
                f32x4 val = *(const f32x4*)(Osm + rb);
                __builtin_nontemporal_store(val, (f32x4*)(outb + (size_t)row * 2048 + j2 * 512 + (f & 511)));
            }
        }
    }
}

// ---------------- launcher ----------------
extern "C" void kernel_launch(void* const* d_in, const int* in_sizes, int n_in,
                              void* d_out, int out_size, void* d_ws, size_t ws_size,
                              hipStream_t stream) {
    const float* x  = (const float*)d_in[0];
    const float* Wq = (const float*)d_in[2];
    const float* bq = (const float*)d_in[3];
    const float* Wk = (const float*)d_in[4];
    const float* bk = (const float*)d_in[5];
    const float* Wv = (const float*)d_in[6];
    const float* bv = (const float*)d_in[7];
    float* out = (float*)d_out;
    char* ws = (char*)d_ws;

    _Float16* Vs  = (_Float16*)ws;                 // 512*4096*2 = 4 MiB (swizzled)
    float* a_arr  = (float*)(ws + 4194304);        // 4096 f32
    float* ks_arr = (float*)(ws + 4210688);        // 4096 f32
    float* part   = (float*)(ws + 4227072);        // [2][4][512] f32 = 16 KB
    float* pbias  = (float*)(ws + 4243456);        // [2] f32

    colsum_vt_kernel<<<520, 256, 0, stream>>>(Wq, bq, Wk, bk, part, pbias, x, Wv, bv, Vs);
    rowdot_kernel<<<1024, 256, 0, stream>>>(x, part, pbias, a_arr, ks_arr);
    attn_main_kernel<<<2048, 256, 0, stream>>>(a_arr, ks_arr, Vs, out);
}